// Round 3
// baseline (454.970 us; speedup 1.0000x reference)
//
#include <hip/hip_runtime.h>
#include <hip/hip_bf16.h>
#include <cstdint>

// ---------------- problem constants ----------------
#define NN      8192      // nodes
#define OF      64        // out features
#define NPAD    80        // 64 h-cols + 1 e-col + 15 zero cols
#define HWROWS  160       // rows 0..79 = bf16 hi, 80..159 = bf16 lo
#define KSPLIT  8

// ---------------- ws layout (bytes) ----------------
#define OFF_H   0                         // h    8192x64 f32    = 2097152
#define OFF_R   2097152                   // r    8192 f32       = 32768
#define OFF_HW  2129920                   // HW   160x8192 u16   = 2621440
#define OFF_P   4751360                   // P8   8x8192x80 f32  = 20971520
// total ~25.7 MB

typedef __attribute__((ext_vector_type(8))) short  s16x8;
typedef __attribute__((ext_vector_type(4))) float  f32x4;

__device__ __forceinline__ unsigned short f2bf(float f) {
  unsigned int u = __float_as_uint(f);
  unsigned int r = (u + 0x7FFFu + ((u >> 16) & 1u)) >> 16;   // RNE
  return (unsigned short)r;
}
__device__ __forceinline__ float bf2f(unsigned short s) {
  return __uint_as_float(((unsigned int)s) << 16);
}

// ---------------- k1: h = X @ W (LDS-tiled fp32), r = h @ a_right ----------------
__global__ __launch_bounds__(256) void k1_h_r(const float* __restrict__ X,
                                              const float* __restrict__ W,
                                              const float* __restrict__ att,
                                              float* __restrict__ h,
                                              float* __restrict__ r) {
  __shared__ float xs[16 * 516];     // stride 516: odd 16B-segment count
  __shared__ float ws[64 * 68];
  int t = threadIdx.x;
  int rb = blockIdx.x * 16;

  { // stage X rows, coalesced float4
    const float4* src = (const float4*)(X + (size_t)rb * 512);
#pragma unroll
    for (int s = 0; s < 8; ++s) {
      int lid = s * 256 + t;
      int row = lid >> 7, kseg = lid & 127;
      *(float4*)&xs[row * 516 + kseg * 4] = src[row * 128 + kseg];
    }
  }

  int row = t >> 4, tx = t & 15;     // thread: 1 row x 4 cols
  float4 acc = {0.f, 0.f, 0.f, 0.f};
  for (int kc = 0; kc < 8; ++kc) {
    __syncthreads();
#pragma unroll
    for (int s = 0; s < 4; ++s) {    // stage W[kc*64 .. +63][0..63]
      int lid = s * 256 + t;
      int k = lid >> 4, cs = lid & 15;
      *(float4*)&ws[k * 68 + cs * 4] =
          *(const float4*)(W + (size_t)(kc * 64 + k) * 64 + cs * 4);
    }
    __syncthreads();
#pragma unroll 16
    for (int k = 0; k < 64; ++k) {
      float x = xs[row * 516 + kc * 64 + k];
      float4 w4 = *(const float4*)&ws[k * 68 + tx * 4];
      acc.x += x * w4.x; acc.y += x * w4.y;
      acc.z += x * w4.z; acc.w += x * w4.w;
    }
  }
  *(float4*)(h + (size_t)(rb + row) * 64 + tx * 4) = acc;

  float v = acc.x * att[64 + tx * 4]     + acc.y * att[64 + tx * 4 + 1] +
            acc.z * att[64 + tx * 4 + 2] + acc.w * att[64 + tx * 4 + 3];
#pragma unroll
  for (int off = 8; off > 0; off >>= 1) v += __shfl_down(v, off, 16);
  if (tx == 0) r[rb + row] = v;
}

// ---------------- k2: HW[n][j]  (transposed B, bf16 hi/lo) ----------------
__global__ __launch_bounds__(256) void k2_hw(const float* __restrict__ h,
                                             const float* __restrict__ r,
                                             unsigned short* __restrict__ HW) {
  int j = blockIdx.x * 256 + threadIdx.x;
  int m = blockIdx.y;                              // 0..159
  float e = expf(r[j]);                            // |r| <~ 21, no overflow
  int n = (m < 80) ? m : m - 80;
  float v;
  if (n < 64)      v = e * h[j * 64 + n];
  else if (n == 64) v = e;
  else             v = 0.f;
  unsigned short hi = f2bf(v);
  unsigned short val = (m < 80) ? hi : f2bf(v - bf2f(hi));
  HW[(size_t)m * NN + j] = val;
}

// ---------------- cvt: 8 int32 {0,1} -> 8 bf16 {0,1} (packed, 8 VALU) -----
__device__ __forceinline__ s16x8 cvt8(int4 a, int4 b) {
  union { unsigned u[4]; s16x8 v; } rr;
  rr.u[0] = (unsigned)(a.x | (a.y << 16)) * 0x3F80u;
  rr.u[1] = (unsigned)(a.z | (a.w << 16)) * 0x3F80u;
  rr.u[2] = (unsigned)(b.x | (b.y << 16)) * 0x3F80u;
  rr.u[3] = (unsigned)(b.z | (b.w << 16)) * 0x3F80u;
  return rr.v;
}

// ---------------- k3: P8[ks] = A-chunk @ B  (no-LDS MFMA, hi/lo) ----------
// B fragments loaded straight global->VGPR (HW is L2-resident); no barriers,
// no LDS bank conflicts, loads of step s+1 pipeline freely over MFMAs of s.
__global__ __launch_bounds__(256, 2) void k3_gat(const int* __restrict__ A,
                                                 const unsigned short* __restrict__ HW,
                                                 float* __restrict__ P) {
  int t = threadIdx.x;
  int rowTile = blockIdx.x >> 3;                   // 0..63  (128 rows each)
  int ksId    = blockIdx.x & 7;                    // K chunk of 1024
  int lane = t & 63, w = t >> 6;
  int l15 = lane & 15, q = lane >> 4;
  int rowBase = rowTile * 128 + w * 32;

  const int* ar0 = A + (size_t)(rowBase + l15) * NN + ksId * (NN / KSPLIT) + q * 8;
  const int* ar1 = ar0 + (size_t)16 * NN;

  const unsigned short* bph[5];
  const unsigned short* bpl[5];
#pragma unroll
  for (int tt = 0; tt < 5; ++tt) {
    bph[tt] = HW + (size_t)(tt * 16 + l15) * NN + ksId * (NN / KSPLIT) + q * 8;
    bpl[tt] = bph[tt] + (size_t)80 * NN;
  }

  f32x4 acc[2][5];
#pragma unroll
  for (int mt = 0; mt < 2; ++mt)
#pragma unroll
    for (int tt = 0; tt < 5; ++tt) acc[mt][tt] = 0.f;

  for (int step = 0; step < (NN / KSPLIT) / 64; ++step) {
    // A: 8x int4 (two row-groups x two 32-k halves)
    int4 a00 = *(const int4*)(ar0);
    int4 a01 = *(const int4*)(ar0 + 4);
    int4 a02 = *(const int4*)(ar0 + 32);
    int4 a03 = *(const int4*)(ar0 + 36);
    int4 a10 = *(const int4*)(ar1);
    int4 a11 = *(const int4*)(ar1 + 4);
    int4 a12 = *(const int4*)(ar1 + 32);
    int4 a13 = *(const int4*)(ar1 + 36);

    // B: 20x 16B fragment loads (L2-resident)
    s16x8 bhi[2][5], blo[2][5];
#pragma unroll
    for (int ks = 0; ks < 2; ++ks)
#pragma unroll
      for (int tt = 0; tt < 5; ++tt) {
        bhi[ks][tt] = *(const s16x8*)(bph[tt] + ks * 32);
        blo[ks][tt] = *(const s16x8*)(bpl[tt] + ks * 32);
      }

    s16x8 af[2][2];
    af[0][0] = cvt8(a00, a01);
    af[0][1] = cvt8(a02, a03);
    af[1][0] = cvt8(a10, a11);
    af[1][1] = cvt8(a12, a13);

#pragma unroll
    for (int ks = 0; ks < 2; ++ks)
#pragma unroll
      for (int tt = 0; tt < 5; ++tt) {
        acc[0][tt] = __builtin_amdgcn_mfma_f32_16x16x32_bf16(af[0][ks], bhi[ks][tt], acc[0][tt], 0, 0, 0);
        acc[1][tt] = __builtin_amdgcn_mfma_f32_16x16x32_bf16(af[1][ks], bhi[ks][tt], acc[1][tt], 0, 0, 0);
        acc[0][tt] = __builtin_amdgcn_mfma_f32_16x16x32_bf16(af[0][ks], blo[ks][tt], acc[0][tt], 0, 0, 0);
        acc[1][tt] = __builtin_amdgcn_mfma_f32_16x16x32_bf16(af[1][ks], blo[ks][tt], acc[1][tt], 0, 0, 0);
      }

    ar0 += 64; ar1 += 64;
#pragma unroll
    for (int tt = 0; tt < 5; ++tt) { bph[tt] += 64; bpl[tt] += 64; }
  }

  // epilogue: plain stores to private slab
  float* Pp = P + (size_t)ksId * NN * NPAD;
#pragma unroll
  for (int mt = 0; mt < 2; ++mt) {
    int rb = rowBase + mt * 16 + q * 4;
#pragma unroll
    for (int tt = 0; tt < 5; ++tt) {
      int col = tt * 16 + l15;
#pragma unroll
      for (int rg = 0; rg < 4; ++rg)
        Pp[(size_t)(rb + rg) * NPAD + col] = acc[mt][tt][rg];
    }
  }
}

// ---------------- k4: reduce slabs + normalize + ELU ----------------
__global__ __launch_bounds__(256) void k4_fin(const float* __restrict__ P,
                                              float* __restrict__ out) {
  int g = blockIdx.x * 256 + threadIdx.x;          // 524288
  int i = g >> 6, c = g & 63;
  float num = 0.f, S = 0.f;
#pragma unroll
  for (int ks = 0; ks < KSPLIT; ++ks) {
    const float* p = P + (size_t)ks * NN * NPAD + (size_t)i * NPAD;
    num += p[c];
    S   += p[64];
  }
  float x = num / S;
  out[g] = x > 0.f ? x : expm1f(x);
}

extern "C" void kernel_launch(void* const* d_in, const int* in_sizes, int n_in,
                              void* d_out, int out_size, void* d_ws, size_t ws_size,
                              hipStream_t stream) {
  const float* X  = (const float*)d_in[0];   // 8192x512
  const int*   A  = (const int*)d_in[1];     // 8192x8192
  const float* W  = (const float*)d_in[2];   // 512x64
  const float* av = (const float*)d_in[3];   // 128x1
  float* out = (float*)d_out;

  char* ws = (char*)d_ws;
  float*          h  = (float*)(ws + OFF_H);
  float*          r  = (float*)(ws + OFF_R);
  unsigned short* HW = (unsigned short*)(ws + OFF_HW);
  float*          P  = (float*)(ws + OFF_P);

  k1_h_r<<<NN / 16, 256, 0, stream>>>(X, W, av, h, r);
  k2_hw<<<dim3(NN / 256, HWROWS), 256, 0, stream>>>(h, r, HW);
  k3_gat<<<64 * KSPLIT, 256, 0, stream>>>(A, HW, P);
  k4_fin<<<(size_t)NN * OF / 256, 256, 0, stream>>>(P, out);
}

// Round 4
// 411.007 us; speedup vs baseline: 1.1070x; 1.1070x over previous
//
#include <hip/hip_runtime.h>
#include <hip/hip_bf16.h>
#include <cstdint>

// ---------------- problem constants ----------------
#define NN      8192      // nodes
#define OF      64        // out features
#define NPAD    80        // 64 h-cols + 1 e-col + 15 zero cols
#define HWROWS  160       // rows 0..79 = bf16 hi, 80..159 = bf16 lo
#define KSPLIT  8
#define LDSTR   72        // LDS k-stride (shorts)

// ---------------- ws layout (bytes) ----------------
#define OFF_HW  0                         // HW   160x8192 u16   = 2621440
#define OFF_P   2621440                   // P8   8x8192x80 f32  = 20971520
// total ~23.6 MB

typedef __attribute__((ext_vector_type(8))) short  s16x8;
typedef __attribute__((ext_vector_type(4))) float  f32x4;

__device__ __forceinline__ unsigned short f2bf(float f) {
  unsigned int u = __float_as_uint(f);
  unsigned int r = (u + 0x7FFFu + ((u >> 16) & 1u)) >> 16;   // RNE
  return (unsigned short)r;
}
__device__ __forceinline__ float bf2f(unsigned short s) {
  return __uint_as_float(((unsigned int)s) << 16);
}

// ---------------- k1: h = X @ W (LDS-tiled fp32) -> fused e/HW write -------
// 512 blocks x 16 rows. Produces HW directly; no h/r round-trip.
__global__ __launch_bounds__(256) void k1_hw(const float* __restrict__ X,
                                             const float* __restrict__ W,
                                             const float* __restrict__ att,
                                             unsigned short* __restrict__ HW) {
  __shared__ float xs[16 * 516];     // stride 516: odd 16B-segment count
  __shared__ float ws[64 * 68];
  int t = threadIdx.x;
  int rb = blockIdx.x * 16;

  { // stage X rows, coalesced float4
    const float4* src = (const float4*)(X + (size_t)rb * 512);
#pragma unroll
    for (int s = 0; s < 8; ++s) {
      int lid = s * 256 + t;
      int row = lid >> 7, kseg = lid & 127;
      *(float4*)&xs[row * 516 + kseg * 4] = src[row * 128 + kseg];
    }
  }

  int row = t >> 4, tx = t & 15;     // thread: 1 row x 4 cols
  float4 acc = {0.f, 0.f, 0.f, 0.f};
  for (int kc = 0; kc < 8; ++kc) {
    __syncthreads();
#pragma unroll
    for (int s = 0; s < 4; ++s) {    // stage W[kc*64 .. +63][0..63]
      int lid = s * 256 + t;
      int k = lid >> 4, cs = lid & 15;
      *(float4*)&ws[k * 68 + cs * 4] =
          *(const float4*)(W + (size_t)(kc * 64 + k) * 64 + cs * 4);
    }
    __syncthreads();
#pragma unroll 16
    for (int k = 0; k < 64; ++k) {
      float x = xs[row * 516 + kc * 64 + k];
      float4 w4 = *(const float4*)&ws[k * 68 + tx * 4];
      acc.x += x * w4.x; acc.y += x * w4.y;
      acc.z += x * w4.z; acc.w += x * w4.w;
    }
  }

  // r = h[row]·a_right, reduced across the 16 tx lanes (all lanes get it)
  float v = acc.x * att[64 + tx * 4]     + acc.y * att[64 + tx * 4 + 1] +
            acc.z * att[64 + tx * 4 + 2] + acc.w * att[64 + tx * 4 + 3];
#pragma unroll
  for (int m = 8; m > 0; m >>= 1) v += __shfl_xor(v, m, 64);
  float e = expf(v);                 // |r| <~ 21, no overflow

  int j = rb + row;
  unsigned short* hw = HW + j;
  float hv[4] = {acc.x, acc.y, acc.z, acc.w};
#pragma unroll
  for (int c = 0; c < 4; ++c) {
    float val = e * hv[c];
    unsigned short hi = f2bf(val);
    hw[(size_t)(tx * 4 + c) * NN]      = hi;
    hw[(size_t)(80 + tx * 4 + c) * NN] = f2bf(val - bf2f(hi));
  }
  if (tx == 0) {
    unsigned short ehi = f2bf(e);
    hw[(size_t)64 * NN]  = ehi;
    hw[(size_t)144 * NN] = f2bf(e - bf2f(ehi));
  } else {
    hw[(size_t)(64 + tx) * NN]  = 0;   // zero-pad cols 65..79 (hi)
    hw[(size_t)(144 + tx) * NN] = 0;   // and lo
  }
}

// ---------------- cvt: 8 int32 {0,1} -> 8 bf16 {0,1} (packed, 8 VALU) -----
__device__ __forceinline__ s16x8 cvt8(int4 a, int4 b) {
  union { unsigned u[4]; s16x8 v; } rr;
  rr.u[0] = (unsigned)(a.x | (a.y << 16)) * 0x3F80u;
  rr.u[1] = (unsigned)(a.z | (a.w << 16)) * 0x3F80u;
  rr.u[2] = (unsigned)(b.x | (b.y << 16)) * 0x3F80u;
  rr.u[3] = (unsigned)(b.z | (b.w << 16)) * 0x3F80u;
  return rr.v;
}

// ---------------- k3: P8[ks] = A-chunk @ B  (MFMA hi/lo, LDS-staged B) ----
// BM=64 (4 waves x 1 m-tile), grid 1024 -> 4 blocks/CU, 16 waves/CU.
__global__ __launch_bounds__(256, 4) void k3_gat(const int* __restrict__ A,
                                                 const unsigned short* __restrict__ HW,
                                                 float* __restrict__ P) {
  __shared__ unsigned short tile[HWROWS * LDSTR];  // 23040 B

  int t = threadIdx.x;
  int rowTile = blockIdx.x >> 3;                   // 0..127 (64 rows each)
  int ksId    = blockIdx.x & 7;                    // K chunk of 1024 (XCD-affine)
  int lane = t & 63, w = t >> 6;
  int l15 = lane & 15, q = lane >> 4;
  int rowBase = rowTile * 64 + w * 16;

  const int* ar0 = A + (size_t)(rowBase + l15) * NN + ksId * (NN / KSPLIT) + q * 8;

  f32x4 acc[5];
#pragma unroll
  for (int tt = 0; tt < 5; ++tt) acc[tt] = 0.f;

  int nrow[5], sg[5];
#pragma unroll
  for (int s = 0; s < 5; ++s) {
    int lid = s * 256 + t;
    nrow[s] = lid >> 3;
    sg[s]   = lid & 7;
  }

  int kk = ksId * (NN / KSPLIT);
  for (int step = 0; step < (NN / KSPLIT) / 64; ++step, kk += 64) {
    uint4 sv[5];
#pragma unroll
    for (int s = 0; s < 5; ++s)
      sv[s] = *(const uint4*)(HW + (size_t)nrow[s] * NN + kk + sg[s] * 8);

    int4 a00 = *(const int4*)(ar0);
    int4 a01 = *(const int4*)(ar0 + 4);
    int4 a02 = *(const int4*)(ar0 + 32);
    int4 a03 = *(const int4*)(ar0 + 36);
    ar0 += 64;

#pragma unroll
    for (int s = 0; s < 5; ++s)
      *(uint4*)&tile[nrow[s] * LDSTR + sg[s] * 8] = sv[s];

    s16x8 af[2];
    af[0] = cvt8(a00, a01);
    af[1] = cvt8(a02, a03);

    __syncthreads();

#pragma unroll
    for (int ks = 0; ks < 2; ++ks)
#pragma unroll
      for (int tt = 0; tt < 5; ++tt) {
        int boff = (tt * 16 + l15) * LDSTR + ks * 32 + q * 8;
        s16x8 bhi = *(const s16x8*)&tile[boff];
        s16x8 blo = *(const s16x8*)&tile[boff + 80 * LDSTR];
        acc[tt] = __builtin_amdgcn_mfma_f32_16x16x32_bf16(af[ks], bhi, acc[tt], 0, 0, 0);
        acc[tt] = __builtin_amdgcn_mfma_f32_16x16x32_bf16(af[ks], blo, acc[tt], 0, 0, 0);
      }
    __syncthreads();
  }

  // epilogue: plain stores to private slab; C/D layout col=l15, row=q*4+reg
  float* Pp = P + (size_t)ksId * NN * NPAD;
  int rb = rowBase + q * 4;
#pragma unroll
  for (int tt = 0; tt < 5; ++tt) {
    int col = tt * 16 + l15;
#pragma unroll
    for (int rg = 0; rg < 4; ++rg)
      Pp[(size_t)(rb + rg) * NPAD + col] = acc[tt][rg];
  }
}

// ---------------- k4: reduce slabs + normalize + ELU ----------------
__global__ __launch_bounds__(256) void k4_fin(const float* __restrict__ P,
                                              float* __restrict__ out) {
  int g = blockIdx.x * 256 + threadIdx.x;          // 524288
  int i = g >> 6, c = g & 63;
  float num = 0.f, S = 0.f;
#pragma unroll
  for (int ks = 0; ks < KSPLIT; ++ks) {
    const float* p = P + (size_t)ks * NN * NPAD + (size_t)i * NPAD;
    num += p[c];
    S   += p[64];
  }
  float x = num / S;
  out[g] = x > 0.f ? x : expm1f(x);
}

extern "C" void kernel_launch(void* const* d_in, const int* in_sizes, int n_in,
                              void* d_out, int out_size, void* d_ws, size_t ws_size,
                              hipStream_t stream) {
  const float* X  = (const float*)d_in[0];   // 8192x512
  const int*   A  = (const int*)d_in[1];     // 8192x8192
  const float* W  = (const float*)d_in[2];   // 512x64
  const float* av = (const float*)d_in[3];   // 128x1
  float* out = (float*)d_out;

  char* ws = (char*)d_ws;
  unsigned short* HW = (unsigned short*)(ws + OFF_HW);
  float*          P  = (float*)(ws + OFF_P);

  k1_hw<<<NN / 16, 256, 0, stream>>>(X, W, av, HW);
  k3_gat<<<128 * KSPLIT, 256, 0, stream>>>(A, HW, P);
  k4_fin<<<(size_t)NN * OF / 256, 256, 0, stream>>>(P, out);
}